// Round 1
// baseline (136.998 us; speedup 1.0000x reference)
//
#include <hip/hip_runtime.h>
#include <hip/hip_bf16.h>

#define SCALE 0.044194173824159216f

typedef float f32x4 __attribute__((ext_vector_type(4)));
typedef __bf16 bf16x8 __attribute__((ext_vector_type(8)));

static __device__ __forceinline__ unsigned short f2bf(float f){
  unsigned u = __builtin_bit_cast(unsigned, f);
  u += 0x7fffu + ((u >> 16) & 1u);
  return (unsigned short)(u >> 16);
}
static __device__ __forceinline__ float bf2f(unsigned short h){
  unsigned u = ((unsigned)h) << 16;
  return __builtin_bit_cast(float, u);
}

// K0: pack w1q|w1k|w1v transposed -> W1T bf16 [192][512]; w2q transposed -> W2qT bf16 [512][64]
__global__ __launch_bounds__(256) void k0_prep(const float* __restrict__ w1q, const float* __restrict__ w1k,
    const float* __restrict__ w1v, const float* __restrict__ w2q,
    unsigned short* __restrict__ W1T, unsigned short* __restrict__ W2qT){
  int id = blockIdx.x * 256 + threadIdx.x;
  if (id < 192*512){
    int n = id >> 9, k = id & 511;
    int p = n >> 6, c = n & 63;
    const float* w1 = (p==0)? w1q : ((p==1)? w1k : w1v);
    W1T[id] = f2bf(w1[k*64 + c]);
  } else if (id < 192*512 + 512*64){
    int j = id - 192*512;
    int e = j >> 6, r = j & 63;
    W2qT[j] = f2bf(w2q[r*512 + e]);
  }
}

// P = scale * Wq~ @ Wk~^T  [65][65]
__global__ __launch_bounds__(256) void k_p(const float* __restrict__ w2q, const float* __restrict__ b2q,
    const float* __restrict__ w2k, const float* __restrict__ b2k, float* __restrict__ Pm){
  int id = blockIdx.x * 256 + threadIdx.x;
  if (id >= 65*65) return;
  int i = id / 65, j = id - i*65;
  const float* qi = (i < 64)? (w2q + i*512) : b2q;
  const float* kj = (j < 64)? (w2k + j*512) : b2k;
  float s = 0.f;
  for (int e = 0; e < 512; e += 4){
    float4 a = *(const float4*)(qi + e);
    float4 b = *(const float4*)(kj + e);
    s += a.x*b.x; s += a.y*b.y; s += a.z*b.z; s += a.w*b.w;
  }
  Pm[id] = s * SCALE;
}

// K1: H = x @ w1 + b1 for q,k,v.  M=16384 N=192 K=512, bf16 MFMA, out bf16.
__global__ __launch_bounds__(256) void k1_proj(const float* __restrict__ x, const unsigned short* __restrict__ W1T,
    const float* __restrict__ b1q, const float* __restrict__ b1k, const float* __restrict__ b1v,
    unsigned short* __restrict__ Hq, unsigned short* __restrict__ Hk, unsigned short* __restrict__ Hv){
  __shared__ unsigned short Ax[64][40];   // pad 32->40 bf16: stride 20 words, conflict-free frag reads
  __shared__ unsigned short Bt[192][40];
  const int t = threadIdx.x;
  const int lane = t & 63, wave = t >> 6;
  const int r0 = blockIdx.x * 64;
  f32x4 acc[12];
  #pragma unroll
  for (int j = 0; j < 12; j++) acc[j] = (f32x4){0.f,0.f,0.f,0.f};
  for (int k0 = 0; k0 < 512; k0 += 32){
    #pragma unroll
    for (int s = 0; s < 2; s++){           // stage A: 64 rows x 32 k (fp32->bf16)
      int i = t + 256*s;
      int r = i >> 3, kq = (i & 7) * 4;
      float4 v = *(const float4*)(x + (size_t)(r0 + r)*512 + k0 + kq);
      ushort4 pk; pk.x = f2bf(v.x); pk.y = f2bf(v.y); pk.z = f2bf(v.z); pk.w = f2bf(v.w);
      *(ushort4*)&Ax[r][kq] = pk;
    }
    #pragma unroll
    for (int s = 0; s < 3; s++){           // stage B: 192 cols x 32 k, already bf16 n-major
      int i = t + 256*s;
      int n = i >> 2, kq = (i & 3) * 8;
      *(uint4*)&Bt[n][kq] = *(const uint4*)(W1T + n*512 + k0 + kq);
    }
    __syncthreads();
    const int arow = (wave << 4) | (lane & 15);
    const int ks = (lane >> 4) * 8;
    bf16x8 af = *(const bf16x8*)&Ax[arow][ks];
    #pragma unroll
    for (int j = 0; j < 12; j++){
      bf16x8 bf = *(const bf16x8*)&Bt[j*16 + (lane & 15)][ks];
      acc[j] = __builtin_amdgcn_mfma_f32_16x16x32_bf16(af, bf, acc[j], 0, 0, 0);
    }
    __syncthreads();
  }
  unsigned short* Hs[3] = {Hq, Hk, Hv};
  const float* b1s[3] = {b1q, b1k, b1v};
  #pragma unroll
  for (int j = 0; j < 12; j++){
    int p = j >> 2;
    int c = ((j & 3) << 4) | (lane & 15);
    float bias = b1s[p][c];
    #pragma unroll
    for (int rg = 0; rg < 4; rg++){
      int row = r0 + (wave << 4) + ((lane >> 4) << 2) + rg;
      Hs[p][(size_t)row*64 + c] = f2bf(acc[j][rg] + bias);
    }
  }
}

// K2a: partial Atil[b][ch] = sum_t m_t * hk~[t]^T hv~[t] over 64-row chunk. [65][65] fp32 partials.
__global__ __launch_bounds__(128) void k2a(const unsigned short* __restrict__ Hk, const unsigned short* __restrict__ Hv,
    const int* __restrict__ mask, float* __restrict__ part){
  __shared__ float ak[64][72];
  __shared__ float av[64][72];
  const int t = threadIdx.x;
  const int b = blockIdx.x >> 5, ch = blockIdx.x & 31;
  const int g0 = b*2048 + ch*64;
  for (int i = t; i < 4096; i += 128){
    int r = i >> 6, c = i & 63;
    float m = (float)mask[g0 + r];
    ak[r][c] = bf2f(Hk[(size_t)(g0 + r)*64 + c]) * m;
    av[r][c] = bf2f(Hv[(size_t)(g0 + r)*64 + c]);
  }
  for (int i = t; i < 512; i += 128){
    int r = i >> 3, c = 64 + (i & 7);
    float m = (float)mask[g0 + r];
    ak[r][c] = (c == 64)? m : 0.f;
    av[r][c] = (c == 64)? 1.f : 0.f;
  }
  __syncthreads();
  if (t < 117){
    int tj = t / 13, ti = t - tj*13;     // 13 x 9 thread grid, 5x8 register tile
    int i0 = ti * 5, j0 = tj * 8;
    float acc[5][8];
    #pragma unroll
    for (int a = 0; a < 5; a++)
      #pragma unroll
      for (int v = 0; v < 8; v++) acc[a][v] = 0.f;
    for (int r = 0; r < 64; r++){
      float a[5], v[8];
      #pragma unroll
      for (int ii = 0; ii < 5; ii++) a[ii] = ak[r][i0 + ii];
      #pragma unroll
      for (int jj = 0; jj < 8; jj++) v[jj] = av[r][j0 + jj];
      #pragma unroll
      for (int ii = 0; ii < 5; ii++)
        #pragma unroll
        for (int jj = 0; jj < 8; jj++) acc[ii][jj] += a[ii] * v[jj];
    }
    float* pout = part + ((size_t)(b*32 + ch)) * 4225;
    #pragma unroll
    for (int ii = 0; ii < 5; ii++){
      int i = i0 + ii;
      #pragma unroll
      for (int jj = 0; jj < 8; jj++){
        int j = j0 + jj;
        if (j < 65) pout[i*65 + j] = acc[ii][jj];
      }
    }
  }
}

// K3: reduce Atil; T1 = P @ Atil; G = T1 @ Wv~ -> GtA bf16 [b][512][64] (e-major) + Gbias fp32 [b][512]
__global__ __launch_bounds__(256) void k3f(const float* __restrict__ part, const float* __restrict__ Pm,
    const float* __restrict__ w2v, const float* __restrict__ b2v,
    unsigned short* __restrict__ GtA, float* __restrict__ Gbias){
  __shared__ float At[65][66];
  __shared__ float T1[65][66];
  const int t = threadIdx.x;
  const int b = blockIdx.x >> 2, ec = (blockIdx.x & 3) << 7;
  for (int id = t; id < 4225; id += 256){
    int i = id / 65, j = id - i*65;
    const float* p = part + (size_t)b*32*4225 + id;
    float s = 0.f;
    #pragma unroll 8
    for (int c = 0; c < 32; c++) s += p[(size_t)c*4225];
    At[i][j] = s;
  }
  __syncthreads();
  for (int id = t; id < 4225; id += 256){
    int i = id / 65, j = id - i*65;
    float s = 0.f;
    for (int k = 0; k < 65; k++) s += Pm[i*65 + k] * At[k][j];
    T1[i][j] = s;
  }
  __syncthreads();
  for (int id = t; id < 65*128; id += 256){
    int r = id >> 7, eo = id & 127, e = ec + eo;
    float s = 0.f;
    for (int j = 0; j < 64; j++) s += T1[r][j] * w2v[j*512 + e];
    s += T1[r][64] * b2v[e];
    if (r < 64) GtA[((size_t)b*512 + e)*64 + r] = f2bf(s);
    else        Gbias[b*512 + e] = s;
  }
}

// K4: per 64-row tile: temp = m_s*(hq@G + Gbias); out = softmax(temp); qout = hq@w2q + b2q
__global__ __launch_bounds__(256) void k4(const unsigned short* __restrict__ Hq, const unsigned short* __restrict__ W2qT,
    const unsigned short* __restrict__ GtA, const float* __restrict__ Gbias, const float* __restrict__ b2q,
    const int* __restrict__ mask, float* __restrict__ out, float* __restrict__ qout){
  __shared__ unsigned short Ab[64][72];    // pad 64->72 bf16: stride 36 words
  __shared__ unsigned short Bb[512][72];
  const int t = threadIdx.x, lane = t & 63, wave = t >> 6;
  const int b = blockIdx.x >> 5, rc = (blockIdx.x & 31) << 6;
  const size_t gr0 = (size_t)b*2048 + rc;
  #pragma unroll
  for (int s = 0; s < 4; s++){             // stage A (bf16 Hq rows)
    int i = t + 256*s;
    int r = i >> 4, c4 = (i & 15) * 4;
    *(ushort4*)&Ab[r][c4] = *(const ushort4*)(Hq + (gr0 + r)*64 + c4);
  }
  const unsigned short* Bsrc = GtA + (size_t)b*512*64;
  #pragma unroll
  for (int s = 0; s < 32; s++){            // stage B = G (bf16, e-major)
    int i = t + 256*s;
    int e = i >> 4, c4 = (i & 15) * 4;
    *(ushort4*)&Bb[e][c4] = *(const ushort4*)(Bsrc + e*64 + c4);
  }
  __syncthreads();
  const int l15 = lane & 15, lg = lane >> 4;
  const int arow = (wave << 4) | l15;
  const int ks = lg * 8;
  bf16x8 a0 = *(const bf16x8*)&Ab[arow][ks];
  bf16x8 a1 = *(const bf16x8*)&Ab[arow][32 + ks];
  f32x4 acc[32];
  #pragma unroll
  for (int f = 0; f < 32; f++) acc[f] = (f32x4){0.f,0.f,0.f,0.f};
  #pragma unroll
  for (int f = 0; f < 32; f++){
    int col = (f << 4) | l15;
    bf16x8 b0 = *(const bf16x8*)&Bb[col][ks];
    bf16x8 b1 = *(const bf16x8*)&Bb[col][32 + ks];
    acc[f] = __builtin_amdgcn_mfma_f32_16x16x32_bf16(a0, b0, acc[f], 0, 0, 0);
    acc[f] = __builtin_amdgcn_mfma_f32_16x16x32_bf16(a1, b1, acc[f], 0, 0, 0);
  }
  float gb[32];
  #pragma unroll
  for (int f = 0; f < 32; f++) gb[f] = Gbias[(b << 9) | (f << 4) | l15];
  #pragma unroll
  for (int rg = 0; rg < 4; rg++){
    int row = rc + (wave << 4) + (lg << 2) + rg;
    float m = (float)mask[b*2048 + row];
    float mx = -3.4e38f;
    #pragma unroll
    for (int f = 0; f < 32; f++){
      float v = (acc[f][rg] + gb[f]) * m;
      acc[f][rg] = v;
      mx = fmaxf(mx, v);
    }
    #pragma unroll
    for (int d = 1; d < 16; d <<= 1) mx = fmaxf(mx, __shfl_xor(mx, d, 64));
    float sum = 0.f;
    #pragma unroll
    for (int f = 0; f < 32; f++){
      float ev = __expf(acc[f][rg] - mx);
      acc[f][rg] = ev;
      sum += ev;
    }
    #pragma unroll
    for (int d = 1; d < 16; d <<= 1) sum += __shfl_xor(sum, d, 64);
    float inv = 1.f / sum;
    float* orow = out + ((size_t)b*2048 + row) * 512;
    #pragma unroll
    for (int f = 0; f < 32; f++) orow[(f << 4) | l15] = acc[f][rg] * inv;
  }
  __syncthreads();
  #pragma unroll
  for (int s = 0; s < 32; s++){            // restage B = W2qT
    int i = t + 256*s;
    int e = i >> 4, c4 = (i & 15) * 4;
    *(ushort4*)&Bb[e][c4] = *(const ushort4*)(W2qT + e*64 + c4);
  }
  __syncthreads();
  #pragma unroll
  for (int f = 0; f < 32; f++) acc[f] = (f32x4){0.f,0.f,0.f,0.f};
  #pragma unroll
  for (int f = 0; f < 32; f++){
    int col = (f << 4) | l15;
    bf16x8 b0 = *(const bf16x8*)&Bb[col][ks];
    bf16x8 b1 = *(const bf16x8*)&Bb[col][32 + ks];
    acc[f] = __builtin_amdgcn_mfma_f32_16x16x32_bf16(a0, b0, acc[f], 0, 0, 0);
    acc[f] = __builtin_amdgcn_mfma_f32_16x16x32_bf16(a1, b1, acc[f], 0, 0, 0);
  }
  #pragma unroll
  for (int f = 0; f < 32; f++){
    int col = (f << 4) | l15;
    float bias = b2q[col];
    #pragma unroll
    for (int rg = 0; rg < 4; rg++){
      int row = rc + (wave << 4) + (lg << 2) + rg;
      qout[((size_t)b*2048 + row) * 512 + col] = acc[f][rg] + bias;
    }
  }
}

extern "C" void kernel_launch(void* const* d_in, const int* in_sizes, int n_in,
                              void* d_out, int out_size, void* d_ws, size_t ws_size,
                              hipStream_t stream){
  const float* x    = (const float*)d_in[0];
  const int*   mask = (const int*)d_in[1];
  const float* q_w1 = (const float*)d_in[2];
  const float* q_b1 = (const float*)d_in[3];
  const float* q_w2 = (const float*)d_in[4];
  const float* q_b2 = (const float*)d_in[5];
  const float* k_w1 = (const float*)d_in[6];
  const float* k_b1 = (const float*)d_in[7];
  const float* k_w2 = (const float*)d_in[8];
  const float* k_b2 = (const float*)d_in[9];
  const float* v_w1 = (const float*)d_in[10];
  const float* v_b1 = (const float*)d_in[11];
  const float* v_w2 = (const float*)d_in[12];
  const float* v_b2 = (const float*)d_in[13];

  char* ws = (char*)d_ws;
  unsigned short* W1T  = (unsigned short*)(ws + 0);         // 196608
  unsigned short* W2qT = (unsigned short*)(ws + 196608);    // 65536
  float*          Pm   = (float*)(ws + 262144);             // 16900 -> pad
  unsigned short* Hq   = (unsigned short*)(ws + 279296);    // 2097152
  unsigned short* Hk   = (unsigned short*)(ws + 2376448);   // 2097152
  unsigned short* Hv   = (unsigned short*)(ws + 4473600);   // 2097152
  float*          part = (float*)(ws + 6570752);            // 4326400
  unsigned short* GtA  = (unsigned short*)(ws + 10897152);  // 524288
  float*          Gbias= (float*)(ws + 11421440);           // 16384

  float* out  = (float*)d_out;
  float* qout = out + (size_t)8*2048*512;

  k0_prep<<<512, 256, 0, stream>>>(q_w1, k_w1, v_w1, q_w2, W1T, W2qT);
  k_p   <<<17, 256, 0, stream>>>(q_w2, q_b2, k_w2, k_b2, Pm);
  k1_proj<<<256, 256, 0, stream>>>(x, W1T, q_b1, k_b1, v_b1, Hq, Hk, Hv);
  k2a   <<<256, 128, 0, stream>>>(Hk, Hv, mask, part);
  k3f   <<<32, 256, 0, stream>>>(part, Pm, v_w2, v_b2, GtA, Gbias);
  k4    <<<256, 256, 0, stream>>>(Hq, W2qT, GtA, Gbias, q_b2, mask, out, qout);
}

// Round 2
// 110.799 us; speedup vs baseline: 1.2364x; 1.2364x over previous
//
#include <hip/hip_runtime.h>
#include <hip/hip_bf16.h>

#define SCALE 0.044194173824159216f

typedef float f32x4 __attribute__((ext_vector_type(4)));
typedef __bf16 bf16x8 __attribute__((ext_vector_type(8)));

static __device__ __forceinline__ unsigned short f2bf(float f){
  unsigned u = __builtin_bit_cast(unsigned, f);
  u += 0x7fffu + ((u >> 16) & 1u);
  return (unsigned short)(u >> 16);
}
static __device__ __forceinline__ float bf2f(unsigned short h){
  unsigned u = ((unsigned)h) << 16;
  return __builtin_bit_cast(float, u);
}

// K0: pack w1q|w1k|w1v transposed -> W1T bf16 [192][512]; w2q transposed -> W2qT bf16 [512][64]
__global__ __launch_bounds__(256) void k0_prep(const float* __restrict__ w1q, const float* __restrict__ w1k,
    const float* __restrict__ w1v, const float* __restrict__ w2q,
    unsigned short* __restrict__ W1T, unsigned short* __restrict__ W2qT){
  int id = blockIdx.x * 256 + threadIdx.x;
  if (id < 192*512){
    int n = id >> 9, k = id & 511;
    int p = n >> 6, c = n & 63;
    const float* w1 = (p==0)? w1q : ((p==1)? w1k : w1v);
    W1T[id] = f2bf(w1[k*64 + c]);
  } else if (id < 192*512 + 512*64){
    int j = id - 192*512;
    int e = j >> 6, r = j & 63;
    W2qT[j] = f2bf(w2q[r*512 + e]);
  }
}

// P = scale * Wq~ @ Wk~^T  [65][65]
__global__ __launch_bounds__(256) void k_p(const float* __restrict__ w2q, const float* __restrict__ b2q,
    const float* __restrict__ w2k, const float* __restrict__ b2k, float* __restrict__ Pm){
  int id = blockIdx.x * 256 + threadIdx.x;
  if (id >= 65*65) return;
  int i = id / 65, j = id - i*65;
  const float* qi = (i < 64)? (w2q + i*512) : b2q;
  const float* kj = (j < 64)? (w2k + j*512) : b2k;
  float s = 0.f;
  for (int e = 0; e < 512; e += 4){
    float4 a = *(const float4*)(qi + e);
    float4 b = *(const float4*)(kj + e);
    s += a.x*b.x; s += a.y*b.y; s += a.z*b.z; s += a.w*b.w;
  }
  Pm[id] = s * SCALE;
}

// K1: H = x @ w1 + b1 for q,k,v.  M=16384 N=192 K=512, bf16 MFMA, out bf16.
__global__ __launch_bounds__(256) void k1_proj(const float* __restrict__ x, const unsigned short* __restrict__ W1T,
    const float* __restrict__ b1q, const float* __restrict__ b1k, const float* __restrict__ b1v,
    unsigned short* __restrict__ Hq, unsigned short* __restrict__ Hk, unsigned short* __restrict__ Hv){
  __shared__ unsigned short Ax[64][40];   // pad 32->40 bf16: stride 20 words, conflict-free frag reads
  __shared__ unsigned short Bt[192][40];
  const int t = threadIdx.x;
  const int lane = t & 63, wave = t >> 6;
  const int r0 = blockIdx.x * 64;
  f32x4 acc[12];
  #pragma unroll
  for (int j = 0; j < 12; j++) acc[j] = (f32x4){0.f,0.f,0.f,0.f};
  for (int k0 = 0; k0 < 512; k0 += 32){
    #pragma unroll
    for (int s = 0; s < 2; s++){           // stage A: 64 rows x 32 k (fp32->bf16)
      int i = t + 256*s;
      int r = i >> 3, kq = (i & 7) * 4;
      float4 v = *(const float4*)(x + (size_t)(r0 + r)*512 + k0 + kq);
      ushort4 pk; pk.x = f2bf(v.x); pk.y = f2bf(v.y); pk.z = f2bf(v.z); pk.w = f2bf(v.w);
      *(ushort4*)&Ax[r][kq] = pk;
    }
    #pragma unroll
    for (int s = 0; s < 3; s++){           // stage B: 192 cols x 32 k, already bf16 n-major
      int i = t + 256*s;
      int n = i >> 2, kq = (i & 3) * 8;
      *(uint4*)&Bt[n][kq] = *(const uint4*)(W1T + n*512 + k0 + kq);
    }
    __syncthreads();
    const int arow = (wave << 4) | (lane & 15);
    const int ks = (lane >> 4) * 8;
    bf16x8 af = *(const bf16x8*)&Ax[arow][ks];
    #pragma unroll
    for (int j = 0; j < 12; j++){
      bf16x8 bf = *(const bf16x8*)&Bt[j*16 + (lane & 15)][ks];
      acc[j] = __builtin_amdgcn_mfma_f32_16x16x32_bf16(af, bf, acc[j], 0, 0, 0);
    }
    __syncthreads();
  }
  unsigned short* Hs[3] = {Hq, Hk, Hv};
  const float* b1s[3] = {b1q, b1k, b1v};
  #pragma unroll
  for (int j = 0; j < 12; j++){
    int p = j >> 2;
    int c = ((j & 3) << 4) | (lane & 15);
    float bias = b1s[p][c];
    #pragma unroll
    for (int rg = 0; rg < 4; rg++){
      int row = r0 + (wave << 4) + ((lane >> 4) << 2) + rg;
      Hs[p][(size_t)row*64 + c] = f2bf(acc[j][rg] + bias);
    }
  }
}

// K2a: partial Atil[b][ch] = sum_t m_t * hk~[t]^T hv~[t] over 64-row chunk.
// partials CHUNK-MINOR: part[(b*4225 + i*65+j)*32 + ch] so k3a reads are coalesced.
__global__ __launch_bounds__(128) void k2a(const unsigned short* __restrict__ Hk, const unsigned short* __restrict__ Hv,
    const int* __restrict__ mask, float* __restrict__ part){
  __shared__ float ak[64][72];
  __shared__ float av[64][72];
  const int t = threadIdx.x;
  const int b = blockIdx.x >> 5, ch = blockIdx.x & 31;
  const int g0 = b*2048 + ch*64;
  for (int i = t; i < 4096; i += 128){
    int r = i >> 6, c = i & 63;
    float m = (float)mask[g0 + r];
    ak[r][c] = bf2f(Hk[(size_t)(g0 + r)*64 + c]) * m;
    av[r][c] = bf2f(Hv[(size_t)(g0 + r)*64 + c]);
  }
  for (int i = t; i < 512; i += 128){
    int r = i >> 3, c = 64 + (i & 7);
    float m = (float)mask[g0 + r];
    ak[r][c] = (c == 64)? m : 0.f;
    av[r][c] = (c == 64)? 1.f : 0.f;
  }
  __syncthreads();
  if (t < 117){
    int tj = t / 13, ti = t - tj*13;     // 13 x 9 thread grid, 5x8 register tile
    int i0 = ti * 5, j0 = tj * 8;
    float acc[5][8];
    #pragma unroll
    for (int a = 0; a < 5; a++)
      #pragma unroll
      for (int v = 0; v < 8; v++) acc[a][v] = 0.f;
    for (int r = 0; r < 64; r++){
      float a[5], v[8];
      #pragma unroll
      for (int ii = 0; ii < 5; ii++) a[ii] = ak[r][i0 + ii];
      #pragma unroll
      for (int jj = 0; jj < 8; jj++) v[jj] = av[r][j0 + jj];
      #pragma unroll
      for (int ii = 0; ii < 5; ii++)
        #pragma unroll
        for (int jj = 0; jj < 8; jj++) acc[ii][jj] += a[ii] * v[jj];
    }
    float* pout = part + ((size_t)b*4225)*32 + ch;
    #pragma unroll
    for (int ii = 0; ii < 5; ii++){
      int i = i0 + ii;
      #pragma unroll
      for (int jj = 0; jj < 8; jj++){
        int j = j0 + jj;
        if (j < 65) pout[(size_t)(i*65 + j)*32] = acc[ii][jj];
      }
    }
  }
}

// K3a: coalesced reduce of 32 chunk-partials -> At[b][4225]
__global__ __launch_bounds__(256) void k3a(const float* __restrict__ part, float* __restrict__ At){
  int b = blockIdx.x / 17;
  int off = (blockIdx.x - b*17) * 256 + threadIdx.x;
  if (off >= 4225) return;
  const float* p = part + ((size_t)b*4225 + off) * 32;
  f32x4 s0 = (f32x4){0.f,0.f,0.f,0.f}, s1 = (f32x4){0.f,0.f,0.f,0.f};
  #pragma unroll
  for (int c = 0; c < 32; c += 8){
    f32x4 a = *(const f32x4*)(p + c);
    f32x4 d = *(const f32x4*)(p + c + 4);
    s0 += a; s1 += d;
  }
  f32x4 s = s0 + s1;
  At[(size_t)b*4225 + off] = s[0] + s[1] + s[2] + s[3];
}

// K3b: fused T1 = P@At ; G-chunk = T1 @ Wv~ -> GtA bf16 [b][512][64] (e-major) + Gbias fp32 [b][512]
// grid = 8 batches x 8 e-chunks of 64
__global__ __launch_bounds__(256) void k3b(const float* __restrict__ At, const float* __restrict__ Pm,
    const float* __restrict__ w2v, const float* __restrict__ b2v,
    unsigned short* __restrict__ GtA, float* __restrict__ Gbias){
  __shared__ float smem[3*65*66];
  float* Pl  = smem;            // [65][66]
  float* Atl = smem + 4290;     // [65][66]
  float* T1l = smem + 8580;     // [65][66]
  const int t = threadIdx.x;
  const int b = blockIdx.x >> 3, ec = (blockIdx.x & 7) << 6;
  for (int id = t; id < 4225; id += 256){
    int i = id / 65, j = id - i*65;
    Pl[i*66 + j]  = Pm[id];
    Atl[i*66 + j] = At[(size_t)b*4225 + id];
  }
  __syncthreads();
  for (int id = t; id < 4225; id += 256){
    int i = id / 65, j = id - i*65;
    float s = 0.f;
    #pragma unroll 13
    for (int k = 0; k < 65; k++) s += Pl[i*66 + k] * Atl[k*66 + j];
    T1l[i*66 + j] = s;
  }
  __syncthreads();
  float* Wl = Pl;               // reuse P's LDS for the w2v e-chunk [64][66]
  for (int id = t; id < 4096; id += 256){
    int j = id >> 6, c = id & 63;
    Wl[j*66 + c] = w2v[j*512 + ec + c];
  }
  __syncthreads();
  for (int id = t; id < 65*64; id += 256){
    int r = id >> 6, c = id & 63, e = ec + c;
    float s = 0.f;
    #pragma unroll 16
    for (int j = 0; j < 64; j++) s += T1l[r*66 + j] * Wl[j*66 + c];
    s += T1l[r*66 + 64] * b2v[e];
    if (r < 64) GtA[((size_t)b*512 + e)*64 + r] = f2bf(s);
    else        Gbias[b*512 + e] = s;
  }
}

// K4: per 64-row tile: temp = m_s*(hq@G + Gbias); out = softmax(temp); qout = hq@w2q + b2q
__global__ __launch_bounds__(256) void k4(const unsigned short* __restrict__ Hq, const unsigned short* __restrict__ W2qT,
    const unsigned short* __restrict__ GtA, const float* __restrict__ Gbias, const float* __restrict__ b2q,
    const int* __restrict__ mask, float* __restrict__ out, float* __restrict__ qout){
  __shared__ unsigned short Ab[64][72];    // pad 64->72 bf16: stride 36 words
  __shared__ unsigned short Bb[512][72];
  const int t = threadIdx.x, lane = t & 63, wave = t >> 6;
  const int b = blockIdx.x >> 5, rc = (blockIdx.x & 31) << 6;
  const size_t gr0 = (size_t)b*2048 + rc;
  #pragma unroll
  for (int s = 0; s < 4; s++){             // stage A (bf16 Hq rows)
    int i = t + 256*s;
    int r = i >> 4, c4 = (i & 15) * 4;
    *(ushort4*)&Ab[r][c4] = *(const ushort4*)(Hq + (gr0 + r)*64 + c4);
  }
  const unsigned short* Bsrc = GtA + (size_t)b*512*64;
  #pragma unroll
  for (int s = 0; s < 32; s++){            // stage B = G (bf16, e-major)
    int i = t + 256*s;
    int e = i >> 4, c4 = (i & 15) * 4;
    *(ushort4*)&Bb[e][c4] = *(const ushort4*)(Bsrc + e*64 + c4);
  }
  __syncthreads();
  const int l15 = lane & 15, lg = lane >> 4;
  const int arow = (wave << 4) | l15;
  const int ks = lg * 8;
  bf16x8 a0 = *(const bf16x8*)&Ab[arow][ks];
  bf16x8 a1 = *(const bf16x8*)&Ab[arow][32 + ks];
  f32x4 acc[32];
  #pragma unroll
  for (int f = 0; f < 32; f++) acc[f] = (f32x4){0.f,0.f,0.f,0.f};
  #pragma unroll
  for (int f = 0; f < 32; f++){
    int col = (f << 4) | l15;
    bf16x8 b0 = *(const bf16x8*)&Bb[col][ks];
    bf16x8 b1 = *(const bf16x8*)&Bb[col][32 + ks];
    acc[f] = __builtin_amdgcn_mfma_f32_16x16x32_bf16(a0, b0, acc[f], 0, 0, 0);
    acc[f] = __builtin_amdgcn_mfma_f32_16x16x32_bf16(a1, b1, acc[f], 0, 0, 0);
  }
  float gb[32];
  #pragma unroll
  for (int f = 0; f < 32; f++) gb[f] = Gbias[(b << 9) | (f << 4) | l15];
  #pragma unroll
  for (int rg = 0; rg < 4; rg++){
    int row = rc + (wave << 4) + (lg << 2) + rg;
    float m = (float)mask[b*2048 + row];
    float mx = -3.4e38f;
    #pragma unroll
    for (int f = 0; f < 32; f++){
      float v = (acc[f][rg] + gb[f]) * m;
      acc[f][rg] = v;
      mx = fmaxf(mx, v);
    }
    #pragma unroll
    for (int d = 1; d < 16; d <<= 1) mx = fmaxf(mx, __shfl_xor(mx, d, 64));
    float sum = 0.f;
    #pragma unroll
    for (int f = 0; f < 32; f++){
      float ev = __expf(acc[f][rg] - mx);
      acc[f][rg] = ev;
      sum += ev;
    }
    #pragma unroll
    for (int d = 1; d < 16; d <<= 1) sum += __shfl_xor(sum, d, 64);
    float inv = 1.f / sum;
    float* orow = out + ((size_t)b*2048 + row) * 512;
    #pragma unroll
    for (int f = 0; f < 32; f++) orow[(f << 4) | l15] = acc[f][rg] * inv;
  }
  __syncthreads();
  #pragma unroll
  for (int s = 0; s < 32; s++){            // restage B = W2qT
    int i = t + 256*s;
    int e = i >> 4, c4 = (i & 15) * 4;
    *(ushort4*)&Bb[e][c4] = *(const ushort4*)(W2qT + e*64 + c4);
  }
  __syncthreads();
  #pragma unroll
  for (int f = 0; f < 32; f++) acc[f] = (f32x4){0.f,0.f,0.f,0.f};
  #pragma unroll
  for (int f = 0; f < 32; f++){
    int col = (f << 4) | l15;
    bf16x8 b0 = *(const bf16x8*)&Bb[col][ks];
    bf16x8 b1 = *(const bf16x8*)&Bb[col][32 + ks];
    acc[f] = __builtin_amdgcn_mfma_f32_16x16x32_bf16(a0, b0, acc[f], 0, 0, 0);
    acc[f] = __builtin_amdgcn_mfma_f32_16x16x32_bf16(a1, b1, acc[f], 0, 0, 0);
  }
  #pragma unroll
  for (int f = 0; f < 32; f++){
    int col = (f << 4) | l15;
    float bias = b2q[col];
    #pragma unroll
    for (int rg = 0; rg < 4; rg++){
      int row = rc + (wave << 4) + (lg << 2) + rg;
      qout[((size_t)b*2048 + row) * 512 + col] = acc[f][rg] + bias;
    }
  }
}

extern "C" void kernel_launch(void* const* d_in, const int* in_sizes, int n_in,
                              void* d_out, int out_size, void* d_ws, size_t ws_size,
                              hipStream_t stream){
  const float* x    = (const float*)d_in[0];
  const int*   mask = (const int*)d_in[1];
  const float* q_w1 = (const float*)d_in[2];
  const float* q_b1 = (const float*)d_in[3];
  const float* q_w2 = (const float*)d_in[4];
  const float* q_b2 = (const float*)d_in[5];
  const float* k_w1 = (const float*)d_in[6];
  const float* k_b1 = (const float*)d_in[7];
  const float* k_w2 = (const float*)d_in[8];
  const float* k_b2 = (const float*)d_in[9];
  const float* v_w1 = (const float*)d_in[10];
  const float* v_b1 = (const float*)d_in[11];
  const float* v_w2 = (const float*)d_in[12];
  const float* v_b2 = (const float*)d_in[13];

  char* ws = (char*)d_ws;
  unsigned short* W1T  = (unsigned short*)(ws + 0);         // 196608
  unsigned short* W2qT = (unsigned short*)(ws + 196608);    // 65536
  float*          Pm   = (float*)(ws + 262144);             // 16900 -> pad
  unsigned short* Hq   = (unsigned short*)(ws + 279296);    // 2097152
  unsigned short* Hk   = (unsigned short*)(ws + 2376448);   // 2097152
  unsigned short* Hv   = (unsigned short*)(ws + 4473600);   // 2097152
  float*          part = (float*)(ws + 6570752);            // 4326400
  float*          At   = (float*)(ws + 10897152);           // 135200 -> pad 135296
  unsigned short* GtA  = (unsigned short*)(ws + 11032448);  // 524288
  float*          Gbias= (float*)(ws + 11556736);           // 16384

  float* out  = (float*)d_out;
  float* qout = out + (size_t)8*2048*512;

  k0_prep<<<512, 256, 0, stream>>>(q_w1, k_w1, v_w1, q_w2, W1T, W2qT);
  k_p   <<<17, 256, 0, stream>>>(q_w2, q_b2, k_w2, k_b2, Pm);
  k1_proj<<<256, 256, 0, stream>>>(x, W1T, q_b1, k_b1, v_b1, Hq, Hk, Hv);
  k2a   <<<256, 128, 0, stream>>>(Hk, Hv, mask, part);
  k3a   <<<136, 256, 0, stream>>>(part, At);
  k3b   <<<64, 256, 0, stream>>>(At, Pm, v_w2, v_b2, GtA, Gbias);
  k4    <<<256, 256, 0, stream>>>(Hq, W2qT, GtA, Gbias, q_b2, mask, out, qout);
}